// Round 13
// baseline (204.936 us; speedup 1.0000x reference)
//
#include <hip/hip_runtime.h>
#include <math.h>

// Problem constants
#define B2     2
#define CIN    31
#define CC     64      // conv out channels / GAT dim
#define NN     4096    // 64*64 nodes
#define NCH    8       // kNN j-splits (512 j each)

typedef short bf16x8 __attribute__((ext_vector_type(8)));
typedef float f32x4  __attribute__((ext_vector_type(4)));

__device__ inline unsigned short f2bf(float f) {
  union { float f; unsigned u; } v; v.f = f;
  unsigned r = (v.u + 0x7fffu + ((v.u >> 16) & 1u)) >> 16;
  return (unsigned short)r;
}
__device__ inline float bf2f(unsigned short h) {
  union { float f; unsigned u; } v; v.u = ((unsigned)h) << 16;
  return v.f;
}

// ---------------- workspace layout (in 4-byte elements) ----------------
constexpr int OF_YN   = 0;                         // [B,N,64] fp32
constexpr int OF_SQ   = OF_YN   + B2*NN*CC;        // [B,N]
constexpr int OF_HCAT = OF_SQ   + B2*NN;           // [B,N,128]
constexpr int OF_FV   = OF_HCAT + B2*NN*128;       // 4 x [B*N]
constexpr int OF_HAGG = OF_FV   + 4*B2*NN;         // [B,N,128]
constexpr int OF_HO   = OF_HAGG + B2*NN*128;       // [B,N,64]
constexpr int OF_FO   = OF_HO   + B2*NN*CC;        // 2 x [B*N]
constexpr int OF_Z    = OF_FO   + 2*B2*NN;         // [B,N,64]
constexpr int OF_PD   = OF_Z    + B2*NN*CC;        // partial top7 dists [B*N][NCH][7]
constexpr int OF_PI   = OF_PD   + B2*NN*NCH*7;     // partial top7 idx (int)
constexpr int OF_NBR  = OF_PI   + B2*NN*NCH*7;     // [B*N][7] neighbor idx (int)
constexpr int OF_WT   = OF_NBR  + B2*NN*7;         // convT weights [9][64][64]
constexpr int OF_WHT  = OF_WT   + 9*64*64;         // head conv weights [279][64]
constexpr int OF_YNH  = OF_WHT  + 279*64;          // bf16 hi [B,N,64] (ushort)
constexpr int OF_YNL  = OF_YNH  + B2*NN*CC/2;      // bf16 lo [B,N,64] (ushort)

// ---------------- K0: weight transposes ----------------
__global__ __launch_bounds__(256) void k_prep(const float* __restrict__ wlast,
                                              const float* __restrict__ whead,
                                              float* __restrict__ wT,
                                              float* __restrict__ whT) {
  int idx = blockIdx.x*256 + threadIdx.x;
  if (idx < 36864) {
    int co = idx & 63, ci = (idx >> 6) & 63, kk = idx >> 12;
    wT[idx] = wlast[(ci*64 + co)*9 + kk];
  } else if (idx < 36864 + 279*64) {
    int j = idx - 36864;
    int c = j & 63, q = j >> 6;
    whT[j] = whead[c*279 + q];
  }
}

// ---------------- K1: head conv + sq + bf16 split (1024 blocks, 4/CU) -------
__global__ __launch_bounds__(256) void k_head(const float* __restrict__ x,
                                              const float* __restrict__ whT,
                                              const float* __restrict__ bias,
                                              float* __restrict__ yn,
                                              float* __restrict__ sq,
                                              unsigned short* __restrict__ ynh,
                                              unsigned short* __restrict__ ynl) {
  int lane = threadIdx.x & 63, wv = threadIdx.x >> 6;
  int gbase = blockIdx.x*8 + wv*2;               // 2 nodes per wave
  __shared__ __align__(16) float patch[4][2][280];
  for (int nn = 0; nn < 2; ++nn) {
    int g = gbase + nn;
    int b = g >> 12, n = g & 4095;
    int oh = n >> 6, ow = n & 63;
    for (int q = lane; q < 279; q += 64) {
      int ci = q / 9, r = q - ci*9;
      int ky = r / 3, kx = r - ky*3;
      int ih = 2*oh - 1 + ky, iw = 2*ow - 1 + kx;
      float v = 0.f;
      if (ih >= 0 && ih < 128 && iw >= 0 && iw < 128)
        v = x[((b*CIN + ci)*128 + ih)*128 + iw];
      patch[wv][nn][q] = v;
    }
  }
  __syncthreads();
  int c = lane;
  float acc[2];
  float bv = bias[c];
  acc[0] = bv; acc[1] = bv;
  for (int q = 0; q < 276; q += 4) {
    float w0 = whT[q*64 + c];
    float w1 = whT[(q+1)*64 + c];
    float w2 = whT[(q+2)*64 + c];
    float w3 = whT[(q+3)*64 + c];
    #pragma unroll
    for (int nn = 0; nn < 2; ++nn) {
      float4 pv = *(const float4*)&patch[wv][nn][q];
      acc[nn] = fmaf(pv.x, w0, acc[nn]);
      acc[nn] = fmaf(pv.y, w1, acc[nn]);
      acc[nn] = fmaf(pv.z, w2, acc[nn]);
      acc[nn] = fmaf(pv.w, w3, acc[nn]);
    }
  }
  for (int q = 276; q < 279; ++q) {
    float wq = whT[q*64 + c];
    #pragma unroll
    for (int nn = 0; nn < 2; ++nn) acc[nn] = fmaf(patch[wv][nn][q], wq, acc[nn]);
  }
  for (int nn = 0; nn < 2; ++nn) {
    int g = gbase + nn;
    float y = acc[nn];
    yn[g*64 + c] = y;
    unsigned short hb = f2bf(y);
    ynh[g*64 + c] = hb;
    ynl[g*64 + c] = f2bf(y - bf2f(hb));
    float s = y*y;
    #pragma unroll
    for (int off = 32; off > 0; off >>= 1) s += __shfl_xor(s, off);
    if (lane == 0) sq[g] = s;
  }
}

// ---------------- K2: MFMA Gram + packed-key top-7, single-buffer LDS -------
// vs knn6: LDS halved (18.7 KB, single buffer) -> 6 blocks/CU at
// launch_bounds(256,6) (VGPR cap 85 > ~68 needed: no spill — knn7's
// (256,8)/cap-64 spilled). Register prefetch keeps next chunk in flight
// during compute; 2 barriers/chunk now, overlapped across 6 blocks/CU.
__global__ __launch_bounds__(256, 6) void k_knn8(const unsigned short* __restrict__ ynh,
                                                 const unsigned short* __restrict__ ynl,
                                                 const float* __restrict__ sq,
                                                 float* __restrict__ pd,
                                                 int* __restrict__ pidx) {
  __shared__ __align__(16) unsigned short Bh[64*72];   // 9216 B
  __shared__ __align__(16) unsigned short Bl[64*72];   // 9216 B
  __shared__ __align__(16) float sqjs[64];             // 256 B

  int b = blockIdx.z, ib = blockIdx.x, jsp = blockIdx.y;
  int i0 = ib*64, jbase = jsp*512;
  int tid = threadIdx.x;
  int lane = tid & 63, w = tid >> 6;
  int quad = lane >> 4, m = lane & 15;

  const unsigned short* ynh_b = ynh + (size_t)b*NN*64;
  const unsigned short* ynl_b = ynl + (size_t)b*NN*64;
  const float* sq_b = sq + b*NN;

  int irow = i0 + w*16 + m;
  bf16x8 bhf0 = *(const bf16x8*)(ynh_b + irow*64 + quad*8);
  bf16x8 bhf1 = *(const bf16x8*)(ynh_b + irow*64 + 32 + quad*8);
  bf16x8 blf0 = *(const bf16x8*)(ynl_b + irow*64 + quad*8);
  bf16x8 blf1 = *(const bf16x8*)(ynl_b + irow*64 + 32 + quad*8);
  float sqi = sq_b[irow];

  unsigned k7[7];
  #pragma unroll
  for (int k = 0; k < 7; ++k) k7[k] = 0xFFFFFFFFu;

  int srow = tid >> 3, oct = tid & 7;

  { // stage chunk 0
    int jt = jbase;
    *(uint4*)&Bh[srow*72 + oct*8]      = *(const uint4*)(ynh_b + (jt + srow)*64 + oct*8);
    *(uint4*)&Bh[(srow+32)*72 + oct*8] = *(const uint4*)(ynh_b + (jt + srow + 32)*64 + oct*8);
    *(uint4*)&Bl[srow*72 + oct*8]      = *(const uint4*)(ynl_b + (jt + srow)*64 + oct*8);
    *(uint4*)&Bl[(srow+32)*72 + oct*8] = *(const uint4*)(ynl_b + (jt + srow + 32)*64 + oct*8);
    if (tid < 64) sqjs[tid] = sq_b[jt + tid];
  }
  __syncthreads();

  #pragma unroll 1
  for (int c = 0; c < 8; ++c) {
    // prefetch next chunk into registers (overlaps with compute below)
    uint4 gh0, gh1, gl0, gl1; float gsq = 0.f;
    if (c < 7) {
      int jt = jbase + (c+1)*64;
      gh0 = *(const uint4*)(ynh_b + (jt + srow)*64 + oct*8);
      gh1 = *(const uint4*)(ynh_b + (jt + srow + 32)*64 + oct*8);
      gl0 = *(const uint4*)(ynl_b + (jt + srow)*64 + oct*8);
      gl1 = *(const uint4*)(ynl_b + (jt + srow + 32)*64 + oct*8);
      if (tid < 64) gsq = sq_b[jt + tid];
    }
    unsigned lc = (unsigned)(c << 4);
    int jt0 = jbase + c*64;
    #pragma unroll
    for (int jn = 0; jn < 4; ++jn) {
      const int ro = (jn*16 + m)*72 + quad*8;
      bf16x8 ajh0 = *(const bf16x8*)&Bh[ro];
      bf16x8 ajh1 = *(const bf16x8*)&Bh[ro + 32];
      bf16x8 ajl0 = *(const bf16x8*)&Bl[ro];
      bf16x8 ajl1 = *(const bf16x8*)&Bl[ro + 32];
      f32x4 sq4 = *(const f32x4*)&sqjs[jn*16 + quad*4];

      f32x4 a = (f32x4){0.f, 0.f, 0.f, 0.f};
      a = __builtin_amdgcn_mfma_f32_16x16x32_bf16(ajh0, bhf0, a, 0, 0, 0);
      a = __builtin_amdgcn_mfma_f32_16x16x32_bf16(ajl0, bhf0, a, 0, 0, 0);
      a = __builtin_amdgcn_mfma_f32_16x16x32_bf16(ajh0, blf0, a, 0, 0, 0);
      a = __builtin_amdgcn_mfma_f32_16x16x32_bf16(ajh1, bhf1, a, 0, 0, 0);
      a = __builtin_amdgcn_mfma_f32_16x16x32_bf16(ajl1, bhf1, a, 0, 0, 0);
      a = __builtin_amdgcn_mfma_f32_16x16x32_bf16(ajh1, blf1, a, 0, 0, 0);

      #pragma unroll
      for (int r = 0; r < 4; ++r) {
        float d2v = fmaf(-2.f, a[r], sqi + sq4[r]);
        d2v = fmaxf(d2v, 0.f);             // == reference clip(d2, 0)
        unsigned mx = (__float_as_uint(d2v) & 0xFFFFFF80u) | (lc + (unsigned)(jn*4 + r));
        #pragma unroll
        for (int t7 = 0; t7 < 7; ++t7) {
          unsigned old = k7[t7];
          k7[t7] = (mx < old) ? mx : old;
          mx     = (mx < old) ? old : mx;
        }
      }
    }
    __syncthreads();                       // all reads of chunk c done
    if (c < 7) {
      *(uint4*)&Bh[srow*72 + oct*8]      = gh0;
      *(uint4*)&Bh[(srow+32)*72 + oct*8] = gh1;
      *(uint4*)&Bl[srow*72 + oct*8]      = gl0;
      *(uint4*)&Bl[(srow+32)*72 + oct*8] = gl1;
      if (tid < 64) sqjs[tid] = gsq;
    }
    __syncthreads();                       // chunk c+1 visible
  }

  // unpack keys -> (truncated d2, global j); merge the row's 4 quads
  float* cd = (float*)&Bh[0];   // 64*28*4 = 7168 B <= 9216
  int*   ci = (int*)&Bl[0];
  int row = w*16 + m;
  #pragma unroll
  for (int k = 0; k < 7; ++k) {
    unsigned key = k7[k];
    int local = key & 127;
    int cch = local >> 4, jn2 = (local >> 2) & 3, r2 = local & 3;
    cd[row*28 + quad*7 + k] = __uint_as_float(key & 0xFFFFFF80u);
    ci[row*28 + quad*7 + k] = jbase + cch*64 + jn2*16 + quad*4 + r2;
  }
  __syncthreads();
  if (tid < 64) {
    float md[7]; int mi[7];
    #pragma unroll
    for (int k = 0; k < 7; ++k) { md[k] = 3.0e38f; mi[k] = 0x7fffffff; }
    for (int e = 0; e < 28; ++e) {
      float d = cd[tid*28 + e]; int jj = ci[tid*28 + e];
      if (d < md[6] || (d == md[6] && jj < mi[6])) {
        int k = 6;
        #pragma unroll
        for (int t = 5; t >= 0; --t)
          if (d < md[t] || (d == md[t] && jj < mi[t])) { md[t+1] = md[t]; mi[t+1] = mi[t]; k = t; }
        md[k] = d; mi[k] = jj;
      }
    }
    int g = b*NN + i0 + tid;
    int base = (g*NCH + jsp)*7;
    #pragma unroll
    for (int k = 0; k < 7; ++k) { pd[base+k] = md[k]; pidx[base+k] = mi[k]; }
  }
}

// ---------------- K4: fused [hcat GEMM + f-vectors] and [top7 merge] --------
__global__ __launch_bounds__(256) void k_hm(const float* __restrict__ yn,
                                            const float* __restrict__ W0,
                                            const float* __restrict__ W1,
                                            const float* __restrict__ a0,
                                            const float* __restrict__ a1,
                                            float* __restrict__ hcat,
                                            float* __restrict__ fv,
                                            const float* __restrict__ pd,
                                            const int* __restrict__ pidx,
                                            int* __restrict__ nbr) {
  __shared__ __align__(16) float yt[16*64];
  int tid = threadIdx.x;
  if (blockIdx.x >= 512) {
    // ---- merge path ----
    int g = (blockIdx.x - 512)*256 + tid;    // 0..8191
    float d7[7]; int x7[7];
    #pragma unroll
    for (int k = 0; k < 7; ++k) { d7[k] = 3.0e38f; x7[k] = 0x7fffffff; }
    int base = g*NCH*7;
    for (int e = 0; e < NCH*7; ++e) {
      float d = pd[base+e]; int jj = pidx[base+e];
      if (d < d7[6]) {
        int k = 6;
        #pragma unroll
        for (int t = 5; t >= 0; --t) {
          if (d < d7[t]) { d7[t+1] = d7[t]; x7[t+1] = x7[t]; k = t; }
        }
        d7[k] = d; x7[k] = jj;
      }
    }
    #pragma unroll
    for (int k = 0; k < 7; ++k) nbr[g*7 + k] = x7[k];
    return;
  }
  // ---- hcat path ----
  int b = blockIdx.x >> 8, n0 = (blockIdx.x & 255)*16;
  int c = tid & 127, ng = tid >> 7, lane = tid & 63;
  float wreg[64];
  {
    const float* Wp = (c < 64) ? (W0 + c) : (W1 + (c - 64));
    #pragma unroll
    for (int k = 0; k < 64; ++k) wreg[k] = Wp[k*64];
  }
  ((float4*)yt)[tid] = ((const float4*)(yn + (b*NN + n0)*64))[tid];
  __syncthreads();
  int head = c >> 6;
  float av1 = head ? a1[lane] : a0[lane];
  float av2 = head ? a1[64 + lane] : a0[64 + lane];
  for (int nn = 0; nn < 8; ++nn) {
    int node = ng*8 + nn;
    const float* yr = yt + node*64;
    float acc = 0.f;
    #pragma unroll
    for (int k4 = 0; k4 < 16; ++k4) {
      float4 yv = *(const float4*)(yr + k4*4);
      acc = fmaf(yv.x, wreg[k4*4+0], acc);
      acc = fmaf(yv.y, wreg[k4*4+1], acc);
      acc = fmaf(yv.z, wreg[k4*4+2], acc);
      acc = fmaf(yv.w, wreg[k4*4+3], acc);
    }
    hcat[(b*NN + n0 + node)*128 + c] = acc;
    float s1 = acc*av1, s2 = acc*av2;
    #pragma unroll
    for (int off = 32; off > 0; off >>= 1) {
      s1 += __shfl_xor(s1, off); s2 += __shfl_xor(s2, off);
    }
    if (lane == 0) {
      int gg = (b << 12) + n0 + node;
      fv[head*16384 + gg] = s1;
      fv[head*16384 + 8192 + gg] = s2;
    }
  }
}

// ---------------- K6: GAT layer1 aggregation (2 heads) + relu (round-9) -----
__global__ __launch_bounds__(256) void k_agg1(const float* __restrict__ hcat,
                                              const float* __restrict__ fv,
                                              const int* __restrict__ nbr,
                                              float* __restrict__ hagg) {
  int g = blockIdx.x*2 + (threadIdx.x >> 7);
  int c = threadIdx.x & 127;
  int b = g >> 12;
  int head = c >> 6;
  int jj[7];
  #pragma unroll
  for (int t = 0; t < 7; ++t) jj[t] = nbr[g*7 + t];
  float f1 = fv[head*16384 + g];
  const float* f2p = fv + head*16384 + 8192 + (b << 12);
  float e[7], mx = -3.0e38f;
  #pragma unroll
  for (int t = 0; t < 7; ++t) {
    float v = f1 + f2p[jj[t]];
    v = (v >= 0.f) ? v : 0.2f*v;
    e[t] = v; mx = fmaxf(mx, v);
  }
  float wgt[7], s = 0.f;
  #pragma unroll
  for (int t = 0; t < 7; ++t) { wgt[t] = expf(e[t] - mx); s += wgt[t]; }
  float acc = 0.f;
  #pragma unroll
  for (int t = 0; t < 7; ++t)
    acc += (wgt[t]/s) * hcat[((b << 12) + jj[t])*128 + c];
  hagg[g*128 + c] = fmaxf(acc, 0.f);
}

// ---------------- K7: ho = hagg @ W_out + fused f-vectors (round-9) ---------
__global__ __launch_bounds__(256) void k_ho(const float* __restrict__ hagg,
                                            const float* __restrict__ Wout,
                                            const float* __restrict__ aout,
                                            float* __restrict__ ho,
                                            float* __restrict__ fo) {
  __shared__ __align__(16) float ht[16*128];
  __shared__ float part[16][64];
  int b = blockIdx.x >> 8, n0 = (blockIdx.x & 255)*16;
  int tid = threadIdx.x;
  int c = tid & 63, g = (tid >> 6) & 1, ng = tid >> 7;
  float wreg[64];
  #pragma unroll
  for (int k = 0; k < 64; ++k) wreg[k] = Wout[(g*64 + k)*64 + c];
  {
    const float4* src = (const float4*)(hagg + (b*NN + n0)*128);
    ((float4*)ht)[tid] = src[tid];
    ((float4*)ht)[tid + 256] = src[tid + 256];
  }
  __syncthreads();
  float accs[8];
  for (int nn = 0; nn < 8; ++nn) {
    int node = ng*8 + nn;
    const float* hr = ht + node*128 + g*64;
    float acc = 0.f;
    #pragma unroll
    for (int k4 = 0; k4 < 16; ++k4) {
      float4 hv = *(const float4*)(hr + k4*4);
      acc = fmaf(hv.x, wreg[k4*4+0], acc);
      acc = fmaf(hv.y, wreg[k4*4+1], acc);
      acc = fmaf(hv.z, wreg[k4*4+2], acc);
      acc = fmaf(hv.w, wreg[k4*4+3], acc);
    }
    accs[nn] = acc;
  }
  if (g == 0) {
    #pragma unroll
    for (int nn = 0; nn < 8; ++nn) part[ng*8 + nn][c] = accs[nn];
  }
  __syncthreads();
  if (g == 1) {
    float av1 = aout[c], av2 = aout[64 + c];
    for (int nn = 0; nn < 8; ++nn) {
      int node = ng*8 + nn;
      float acc = accs[nn] + part[node][c];
      ho[(b*NN + n0 + node)*64 + c] = acc;
      float s1 = acc*av1, s2 = acc*av2;
      #pragma unroll
      for (int off = 32; off > 0; off >>= 1) {
        s1 += __shfl_xor(s1, off); s2 += __shfl_xor(s2, off);
      }
      if (c == 0) {
        int gg = (b << 12) + n0 + node;
        fo[gg] = s1;
        fo[8192 + gg] = s2;
      }
    }
  }
}

// ---------------- K9: layer2 agg + elu + log_softmax ------------------------
__global__ __launch_bounds__(256) void k_agg2(const float* __restrict__ ho,
                                              const float* __restrict__ fo,
                                              const int* __restrict__ nbr,
                                              float* __restrict__ zbuf) {
  int g = blockIdx.x*4 + (threadIdx.x >> 6);
  int c = threadIdx.x & 63;
  int b = g >> 12;
  int jj[7];
  #pragma unroll
  for (int t = 0; t < 7; ++t) jj[t] = nbr[g*7 + t];
  float f1 = fo[g];
  const float* f2p = fo + 8192 + (b << 12);
  float e[7], mx = -3.0e38f;
  #pragma unroll
  for (int t = 0; t < 7; ++t) {
    float v = f1 + f2p[jj[t]];
    v = (v >= 0.f) ? v : 0.2f*v;
    e[t] = v; mx = fmaxf(mx, v);
  }
  float wgt[7], s = 0.f;
  #pragma unroll
  for (int t = 0; t < 7; ++t) { wgt[t] = expf(e[t] - mx); s += wgt[t]; }
  float acc = 0.f;
  #pragma unroll
  for (int t = 0; t < 7; ++t)
    acc += (wgt[t]/s) * ho[((b << 12) + jj[t])*64 + c];
  float v = (acc > 0.f) ? acc : expm1f(acc);
  float mm = v;
  #pragma unroll
  for (int off = 32; off > 0; off >>= 1) mm = fmaxf(mm, __shfl_xor(mm, off));
  float ex = expf(v - mm), ss = ex;
  #pragma unroll
  for (int off = 32; off > 0; off >>= 1) ss += __shfl_xor(ss, off);
  zbuf[g*64 + c] = v - mm - logf(ss);
}

// ---------------- K10: ConvTranspose2d v4 (round-9 proven) ------------------
__global__ __launch_bounds__(256, 4) void k_convt4(const float* __restrict__ z,
                                                   const float* __restrict__ wT,
                                                   const float* __restrict__ bias,
                                                   float* __restrict__ out) {
  __shared__ __align__(16) float lds[8704];    // 34816 B
  float* zt = lds;              // [2 rows][64 ci][36]
  float* ws = lds + 4608;       // [64 ci][64 co]
  float* so = lds;              // [64 co][65] epilogue alias

  int oy = blockIdx.x, xh = blockIdx.y, b = blockIdx.z;
  int r = oy >> 1, pi = oy & 1;
  int tid = threadIdx.x;
  int colo = tid & 15, pgrp = tid >> 4;
  int co4 = colo*4, m0 = pgrp*2;
  int ix0 = xh*32;

  int nrows = pi ? 2 : 1;
  for (int row = 0; row < nrows; ++row) {
    int iy = r + row;
    const float* zsrc = z + (((b << 12) + iy*64) << 6);
    float4 v[3];
    #pragma unroll
    for (int j = 0; j < 3; ++j) {
      int chunk = tid + j*256;                 // 528 chunks = 33 ix x 16 ci4
      float4 vv = {0.f, 0.f, 0.f, 0.f};
      if (chunk < 528) {
        int ix = chunk >> 4, ci4 = (chunk & 15) << 2;
        int ixg = ix0 + ix;
        if (ixg < 64 && iy < 64) vv = *(const float4*)(zsrc + ixg*64 + ci4);
      }
      v[j] = vv;
    }
    #pragma unroll
    for (int j = 0; j < 3; ++j) {
      int chunk = tid + j*256;
      if (chunk < 528) {
        int ix = chunk >> 4, ci4 = (chunk & 15) << 2;
        zt[row*2304 + (ci4+0)*36 + ix] = v[j].x;
        zt[row*2304 + (ci4+1)*36 + ix] = v[j].y;
        zt[row*2304 + (ci4+2)*36 + ix] = v[j].z;
        zt[row*2304 + (ci4+3)*36 + ix] = v[j].w;
      }
    }
  }

  float acc[2][2][4];
  {
    float4 bv = *(const float4*)&bias[co4];
    #pragma unroll
    for (int chi = 0; chi < 2; ++chi)
      #pragma unroll
      for (int k = 0; k < 2; ++k) {
        acc[chi][k][0] = bv.x; acc[chi][k][1] = bv.y;
        acc[chi][k][2] = bv.z; acc[chi][k][3] = bv.w;
      }
  }

  int kys[2], rows[2], nky;
  if (pi == 0) { kys[0] = 1; rows[0] = 0; nky = 1; }
  else         { kys[0] = 2; rows[0] = 0; kys[1] = 0; rows[1] = 1; nky = 2; }

  for (int t = 0; t < nky; ++t) {
    const float* zrow = zt + rows[t]*2304;
    for (int kx = 0; kx < 3; ++kx) {
      const float* wsrc = wT + (kys[t]*3 + kx)*4096;
      __syncthreads();
      {
        float4 wv4[4];
        #pragma unroll
        for (int j = 0; j < 4; ++j)
          wv4[j] = *(const float4*)(wsrc + (tid + j*256)*4);
        #pragma unroll
        for (int j = 0; j < 4; ++j)
          *(float4*)&ws[(tid + j*256)*4] = wv4[j];
      }
      __syncthreads();
      const int chi = (kx == 1) ? 0 : 1;
      const int xoff = (kx == 0) ? 1 : 0;
      float* ap = &acc[chi][0][0];
      for (int ci = 0; ci < 64; ++ci) {
        float4 wv = *(const float4*)&ws[ci*64 + co4];
        const float* zp = zrow + ci*36 + m0;
        float z0, z1;
        if (xoff == 0) { float2 za = *(const float2*)zp; z0 = za.x; z1 = za.y; }
        else           { float2 za = *(const float2*)zp; z0 = za.y; z1 = zp[2]; }
        ap[0] = fmaf(z0, wv.x, ap[0]);
        ap[1] = fmaf(z0, wv.y, ap[1]);
        ap[2] = fmaf(z0, wv.z, ap[2]);
        ap[3] = fmaf(z0, wv.w, ap[3]);
        ap[4] = fmaf(z1, wv.x, ap[4]);
        ap[5] = fmaf(z1, wv.y, ap[5]);
        ap[6] = fmaf(z1, wv.z, ap[6]);
        ap[7] = fmaf(z1, wv.w, ap[7]);
      }
    }
  }

  __syncthreads();
  #pragma unroll
  for (int chi = 0; chi < 2; ++chi)
    #pragma unroll
    for (int k = 0; k < 2; ++k)
      #pragma unroll
      for (int cc = 0; cc < 4; ++cc)
        so[(co4 + cc)*65 + 2*(m0 + k) + chi] = acc[chi][k][cc];
  __syncthreads();
  for (int idx = tid; idx < 4096; idx += 256) {
    int co = idx >> 6, ox = idx & 63;
    out[(((b << 6) + co)*128 + oy)*128 + xh*64 + ox] = so[co*65 + ox];
  }
}

// ---------------- launch ----------------------------------------------------
extern "C" void kernel_launch(void* const* d_in, const int* in_sizes, int n_in,
                              void* d_out, int out_size, void* d_ws, size_t ws_size,
                              hipStream_t stream) {
  const float* x      = (const float*)d_in[0];
  const float* w_head = (const float*)d_in[1];
  const float* b_head = (const float*)d_in[2];
  const float* W0     = (const float*)d_in[3];
  const float* a0     = (const float*)d_in[4];
  const float* W1     = (const float*)d_in[5];
  const float* a1     = (const float*)d_in[6];
  const float* W_out  = (const float*)d_in[7];
  const float* a_out  = (const float*)d_in[8];
  const float* w_last = (const float*)d_in[9];
  const float* b_last = (const float*)d_in[10];
  float* out = (float*)d_out;

  float* wsf = (float*)d_ws;
  int*   wsi = (int*)d_ws;
  float* yn   = wsf + OF_YN;
  float* sq   = wsf + OF_SQ;
  float* hcat = wsf + OF_HCAT;
  float* fv   = wsf + OF_FV;
  float* hagg = wsf + OF_HAGG;
  float* ho   = wsf + OF_HO;
  float* fo   = wsf + OF_FO;
  float* zbuf = wsf + OF_Z;
  float* pd   = wsf + OF_PD;
  int*   pidx = wsi + OF_PI;
  int*   nbr  = wsi + OF_NBR;
  float* wT   = wsf + OF_WT;
  float* whT  = wsf + OF_WHT;
  unsigned short* ynh = (unsigned short*)(wsf + OF_YNH);
  unsigned short* ynl = (unsigned short*)(wsf + OF_YNL);

  hipLaunchKernelGGL(k_prep,  dim3(214), dim3(256), 0, stream, w_last, w_head, wT, whT);
  hipLaunchKernelGGL(k_head,  dim3(1024), dim3(256), 0, stream, x, whT, b_head, yn, sq, ynh, ynl);
  hipLaunchKernelGGL(k_knn8,  dim3(64, NCH, 2), dim3(256), 0, stream, ynh, ynl, sq, pd, pidx);
  hipLaunchKernelGGL(k_hm,    dim3(544), dim3(256), 0, stream, yn, W0, W1, a0, a1, hcat, fv, pd, pidx, nbr);
  hipLaunchKernelGGL(k_agg1,  dim3(4096), dim3(256), 0, stream, hcat, fv, nbr, hagg);
  hipLaunchKernelGGL(k_ho,    dim3(512), dim3(256), 0, stream, hagg, W_out, a_out, ho, fo);
  hipLaunchKernelGGL(k_agg2,  dim3(2048), dim3(256), 0, stream, ho, fo, nbr, zbuf);
  hipLaunchKernelGGL(k_convt4, dim3(128, 2, 2), dim3(256), 0, stream, zbuf, wT, b_last, out);
}

// Round 14
// 197.030 us; speedup vs baseline: 1.0401x; 1.0401x over previous
//
#include <hip/hip_runtime.h>
#include <math.h>

// Problem constants
#define B2     2
#define CIN    31
#define CC     64      // conv out channels / GAT dim
#define NN     4096    // 64*64 nodes
#define NCH    8       // kNN j-splits (512 j each)

typedef short bf16x8 __attribute__((ext_vector_type(8)));
typedef float f32x4  __attribute__((ext_vector_type(4)));

__device__ inline unsigned short f2bf(float f) {
  union { float f; unsigned u; } v; v.f = f;
  unsigned r = (v.u + 0x7fffu + ((v.u >> 16) & 1u)) >> 16;
  return (unsigned short)r;
}
__device__ inline float bf2f(unsigned short h) {
  union { float f; unsigned u; } v; v.u = ((unsigned)h) << 16;
  return v.f;
}

// ---------------- workspace layout (in 4-byte elements) ----------------
constexpr int OF_YN   = 0;                         // [B,N,64] fp32
constexpr int OF_SQ   = OF_YN   + B2*NN*CC;        // [B,N]
constexpr int OF_HCAT = OF_SQ   + B2*NN;           // [B,N,128]
constexpr int OF_FV   = OF_HCAT + B2*NN*128;       // 4 x [B*N]
constexpr int OF_HAGG = OF_FV   + 4*B2*NN;         // [B,N,128]
constexpr int OF_HO   = OF_HAGG + B2*NN*128;       // [B,N,64]
constexpr int OF_FO   = OF_HO   + B2*NN*CC;        // 2 x [B*N]
constexpr int OF_Z    = OF_FO   + 2*B2*NN;         // [B,N,64]
constexpr int OF_PD   = OF_Z    + B2*NN*CC;        // partial top7 dists [B*N][NCH][7]
constexpr int OF_PI   = OF_PD   + B2*NN*NCH*7;     // partial top7 idx (int)
constexpr int OF_NBR  = OF_PI   + B2*NN*NCH*7;     // [B*N][7] neighbor idx (int)
constexpr int OF_WT   = OF_NBR  + B2*NN*7;         // convT weights [9][64][64]
constexpr int OF_WHT  = OF_WT   + 9*64*64;         // head conv weights [279][64]
constexpr int OF_YNH  = OF_WHT  + 279*64;          // bf16 hi [B,N,64] (ushort)
constexpr int OF_YNL  = OF_YNH  + B2*NN*CC/2;      // bf16 lo [B,N,64] (ushort)

// ---------------- K0: weight transposes ----------------
__global__ __launch_bounds__(256) void k_prep(const float* __restrict__ wlast,
                                              const float* __restrict__ whead,
                                              float* __restrict__ wT,
                                              float* __restrict__ whT) {
  int idx = blockIdx.x*256 + threadIdx.x;
  if (idx < 36864) {
    int co = idx & 63, ci = (idx >> 6) & 63, kk = idx >> 12;
    wT[idx] = wlast[(ci*64 + co)*9 + kk];
  } else if (idx < 36864 + 279*64) {
    int j = idx - 36864;
    int c = j & 63, q = j >> 6;
    whT[j] = whead[c*279 + q];
  }
}

// ---------------- K1: head conv + sq + bf16 split (1024 blocks, 4/CU) -------
__global__ __launch_bounds__(256) void k_head(const float* __restrict__ x,
                                              const float* __restrict__ whT,
                                              const float* __restrict__ bias,
                                              float* __restrict__ yn,
                                              float* __restrict__ sq,
                                              unsigned short* __restrict__ ynh,
                                              unsigned short* __restrict__ ynl) {
  int lane = threadIdx.x & 63, wv = threadIdx.x >> 6;
  int gbase = blockIdx.x*8 + wv*2;               // 2 nodes per wave
  __shared__ __align__(16) float patch[4][2][280];
  for (int nn = 0; nn < 2; ++nn) {
    int g = gbase + nn;
    int b = g >> 12, n = g & 4095;
    int oh = n >> 6, ow = n & 63;
    for (int q = lane; q < 279; q += 64) {
      int ci = q / 9, r = q - ci*9;
      int ky = r / 3, kx = r - ky*3;
      int ih = 2*oh - 1 + ky, iw = 2*ow - 1 + kx;
      float v = 0.f;
      if (ih >= 0 && ih < 128 && iw >= 0 && iw < 128)
        v = x[((b*CIN + ci)*128 + ih)*128 + iw];
      patch[wv][nn][q] = v;
    }
  }
  __syncthreads();
  int c = lane;
  float acc[2];
  float bv = bias[c];
  acc[0] = bv; acc[1] = bv;
  for (int q = 0; q < 276; q += 4) {
    float w0 = whT[q*64 + c];
    float w1 = whT[(q+1)*64 + c];
    float w2 = whT[(q+2)*64 + c];
    float w3 = whT[(q+3)*64 + c];
    #pragma unroll
    for (int nn = 0; nn < 2; ++nn) {
      float4 pv = *(const float4*)&patch[wv][nn][q];
      acc[nn] = fmaf(pv.x, w0, acc[nn]);
      acc[nn] = fmaf(pv.y, w1, acc[nn]);
      acc[nn] = fmaf(pv.z, w2, acc[nn]);
      acc[nn] = fmaf(pv.w, w3, acc[nn]);
    }
  }
  for (int q = 276; q < 279; ++q) {
    float wq = whT[q*64 + c];
    #pragma unroll
    for (int nn = 0; nn < 2; ++nn) acc[nn] = fmaf(patch[wv][nn][q], wq, acc[nn]);
  }
  for (int nn = 0; nn < 2; ++nn) {
    int g = gbase + nn;
    float y = acc[nn];
    yn[g*64 + c] = y;
    unsigned short hb = f2bf(y);
    ynh[g*64 + c] = hb;
    ynl[g*64 + c] = f2bf(y - bf2f(hb));
    float s = y*y;
    #pragma unroll
    for (int off = 32; off > 0; off >>= 1) s += __shfl_xor(s, off);
    if (lane == 0) sq[g] = s;
  }
}

// ---------------- K2: MFMA Gram + packed-key top-7, single-buffer LDS -------
// knn8 structure (single 18.7 KB buffer + register prefetch) but with
// launch_bounds(256,4): min-waves 6/8 forced VGPR caps that SPILLED
// (knn7: VGPR=32, knn8: VGPR=40, WRITE_SIZE 3.6->29MB). At cap 128 the
// body needs ~70 VGPR -> no spill; residency = min(LDS 8, VGPR ~7) blocks/CU.
__global__ __launch_bounds__(256, 4) void k_knn9(const unsigned short* __restrict__ ynh,
                                                 const unsigned short* __restrict__ ynl,
                                                 const float* __restrict__ sq,
                                                 float* __restrict__ pd,
                                                 int* __restrict__ pidx) {
  __shared__ __align__(16) unsigned short Bh[64*72];   // 9216 B
  __shared__ __align__(16) unsigned short Bl[64*72];   // 9216 B
  __shared__ __align__(16) float sqjs[64];             // 256 B

  int b = blockIdx.z, ib = blockIdx.x, jsp = blockIdx.y;
  int i0 = ib*64, jbase = jsp*512;
  int tid = threadIdx.x;
  int lane = tid & 63, w = tid >> 6;
  int quad = lane >> 4, m = lane & 15;

  const unsigned short* ynh_b = ynh + (size_t)b*NN*64;
  const unsigned short* ynl_b = ynl + (size_t)b*NN*64;
  const float* sq_b = sq + b*NN;

  int irow = i0 + w*16 + m;
  bf16x8 bhf0 = *(const bf16x8*)(ynh_b + irow*64 + quad*8);
  bf16x8 bhf1 = *(const bf16x8*)(ynh_b + irow*64 + 32 + quad*8);
  bf16x8 blf0 = *(const bf16x8*)(ynl_b + irow*64 + quad*8);
  bf16x8 blf1 = *(const bf16x8*)(ynl_b + irow*64 + 32 + quad*8);
  float sqi = sq_b[irow];

  unsigned k7[7];
  #pragma unroll
  for (int k = 0; k < 7; ++k) k7[k] = 0xFFFFFFFFu;

  int srow = tid >> 3, oct = tid & 7;

  { // stage chunk 0
    int jt = jbase;
    *(uint4*)&Bh[srow*72 + oct*8]      = *(const uint4*)(ynh_b + (jt + srow)*64 + oct*8);
    *(uint4*)&Bh[(srow+32)*72 + oct*8] = *(const uint4*)(ynh_b + (jt + srow + 32)*64 + oct*8);
    *(uint4*)&Bl[srow*72 + oct*8]      = *(const uint4*)(ynl_b + (jt + srow)*64 + oct*8);
    *(uint4*)&Bl[(srow+32)*72 + oct*8] = *(const uint4*)(ynl_b + (jt + srow + 32)*64 + oct*8);
    if (tid < 64) sqjs[tid] = sq_b[jt + tid];
  }
  __syncthreads();

  #pragma unroll 1
  for (int c = 0; c < 8; ++c) {
    // prefetch next chunk into registers (overlaps with compute below)
    uint4 gh0, gh1, gl0, gl1; float gsq = 0.f;
    if (c < 7) {
      int jt = jbase + (c+1)*64;
      gh0 = *(const uint4*)(ynh_b + (jt + srow)*64 + oct*8);
      gh1 = *(const uint4*)(ynh_b + (jt + srow + 32)*64 + oct*8);
      gl0 = *(const uint4*)(ynl_b + (jt + srow)*64 + oct*8);
      gl1 = *(const uint4*)(ynl_b + (jt + srow + 32)*64 + oct*8);
      if (tid < 64) gsq = sq_b[jt + tid];
    }
    unsigned lc = (unsigned)(c << 4);
    #pragma unroll
    for (int jn = 0; jn < 4; ++jn) {
      const int ro = (jn*16 + m)*72 + quad*8;
      bf16x8 ajh0 = *(const bf16x8*)&Bh[ro];
      bf16x8 ajh1 = *(const bf16x8*)&Bh[ro + 32];
      bf16x8 ajl0 = *(const bf16x8*)&Bl[ro];
      bf16x8 ajl1 = *(const bf16x8*)&Bl[ro + 32];
      f32x4 sq4 = *(const f32x4*)&sqjs[jn*16 + quad*4];

      f32x4 a = (f32x4){0.f, 0.f, 0.f, 0.f};
      a = __builtin_amdgcn_mfma_f32_16x16x32_bf16(ajh0, bhf0, a, 0, 0, 0);
      a = __builtin_amdgcn_mfma_f32_16x16x32_bf16(ajl0, bhf0, a, 0, 0, 0);
      a = __builtin_amdgcn_mfma_f32_16x16x32_bf16(ajh0, blf0, a, 0, 0, 0);
      a = __builtin_amdgcn_mfma_f32_16x16x32_bf16(ajh1, bhf1, a, 0, 0, 0);
      a = __builtin_amdgcn_mfma_f32_16x16x32_bf16(ajl1, bhf1, a, 0, 0, 0);
      a = __builtin_amdgcn_mfma_f32_16x16x32_bf16(ajh1, blf1, a, 0, 0, 0);

      #pragma unroll
      for (int r = 0; r < 4; ++r) {
        float d2v = fmaf(-2.f, a[r], sqi + sq4[r]);
        d2v = fmaxf(d2v, 0.f);             // == reference clip(d2, 0)
        unsigned mx = (__float_as_uint(d2v) & 0xFFFFFF80u) | (lc + (unsigned)(jn*4 + r));
        #pragma unroll
        for (int t7 = 0; t7 < 7; ++t7) {
          unsigned old = k7[t7];
          k7[t7] = (mx < old) ? mx : old;
          mx     = (mx < old) ? old : mx;
        }
      }
    }
    __syncthreads();                       // all reads of chunk c done
    if (c < 7) {
      *(uint4*)&Bh[srow*72 + oct*8]      = gh0;
      *(uint4*)&Bh[(srow+32)*72 + oct*8] = gh1;
      *(uint4*)&Bl[srow*72 + oct*8]      = gl0;
      *(uint4*)&Bl[(srow+32)*72 + oct*8] = gl1;
      if (tid < 64) sqjs[tid] = gsq;
    }
    __syncthreads();                       // chunk c+1 visible
  }

  // unpack keys -> (truncated d2, global j); merge the row's 4 quads
  float* cd = (float*)&Bh[0];   // 64*28*4 = 7168 B <= 9216
  int*   ci = (int*)&Bl[0];
  int row = w*16 + m;
  #pragma unroll
  for (int k = 0; k < 7; ++k) {
    unsigned key = k7[k];
    int local = key & 127;
    int cch = local >> 4, jn2 = (local >> 2) & 3, r2 = local & 3;
    cd[row*28 + quad*7 + k] = __uint_as_float(key & 0xFFFFFF80u);
    ci[row*28 + quad*7 + k] = jbase + cch*64 + jn2*16 + quad*4 + r2;
  }
  __syncthreads();
  if (tid < 64) {
    float md[7]; int mi[7];
    #pragma unroll
    for (int k = 0; k < 7; ++k) { md[k] = 3.0e38f; mi[k] = 0x7fffffff; }
    for (int e = 0; e < 28; ++e) {
      float d = cd[tid*28 + e]; int jj = ci[tid*28 + e];
      if (d < md[6] || (d == md[6] && jj < mi[6])) {
        int k = 6;
        #pragma unroll
        for (int t = 5; t >= 0; --t)
          if (d < md[t] || (d == md[t] && jj < mi[t])) { md[t+1] = md[t]; mi[t+1] = mi[t]; k = t; }
        md[k] = d; mi[k] = jj;
      }
    }
    int g = b*NN + i0 + tid;
    int base = (g*NCH + jsp)*7;
    #pragma unroll
    for (int k = 0; k < 7; ++k) { pd[base+k] = md[k]; pidx[base+k] = mi[k]; }
  }
}

// ---------------- K4: fused [hcat GEMM + f-vectors] and [top7 merge] --------
__global__ __launch_bounds__(256) void k_hm(const float* __restrict__ yn,
                                            const float* __restrict__ W0,
                                            const float* __restrict__ W1,
                                            const float* __restrict__ a0,
                                            const float* __restrict__ a1,
                                            float* __restrict__ hcat,
                                            float* __restrict__ fv,
                                            const float* __restrict__ pd,
                                            const int* __restrict__ pidx,
                                            int* __restrict__ nbr) {
  __shared__ __align__(16) float yt[16*64];
  int tid = threadIdx.x;
  if (blockIdx.x >= 512) {
    // ---- merge path ----
    int g = (blockIdx.x - 512)*256 + tid;    // 0..8191
    float d7[7]; int x7[7];
    #pragma unroll
    for (int k = 0; k < 7; ++k) { d7[k] = 3.0e38f; x7[k] = 0x7fffffff; }
    int base = g*NCH*7;
    for (int e = 0; e < NCH*7; ++e) {
      float d = pd[base+e]; int jj = pidx[base+e];
      if (d < d7[6]) {
        int k = 6;
        #pragma unroll
        for (int t = 5; t >= 0; --t) {
          if (d < d7[t]) { d7[t+1] = d7[t]; x7[t+1] = x7[t]; k = t; }
        }
        d7[k] = d; x7[k] = jj;
      }
    }
    #pragma unroll
    for (int k = 0; k < 7; ++k) nbr[g*7 + k] = x7[k];
    return;
  }
  // ---- hcat path ----
  int b = blockIdx.x >> 8, n0 = (blockIdx.x & 255)*16;
  int c = tid & 127, ng = tid >> 7, lane = tid & 63;
  float wreg[64];
  {
    const float* Wp = (c < 64) ? (W0 + c) : (W1 + (c - 64));
    #pragma unroll
    for (int k = 0; k < 64; ++k) wreg[k] = Wp[k*64];
  }
  ((float4*)yt)[tid] = ((const float4*)(yn + (b*NN + n0)*64))[tid];
  __syncthreads();
  int head = c >> 6;
  float av1 = head ? a1[lane] : a0[lane];
  float av2 = head ? a1[64 + lane] : a0[64 + lane];
  for (int nn = 0; nn < 8; ++nn) {
    int node = ng*8 + nn;
    const float* yr = yt + node*64;
    float acc = 0.f;
    #pragma unroll
    for (int k4 = 0; k4 < 16; ++k4) {
      float4 yv = *(const float4*)(yr + k4*4);
      acc = fmaf(yv.x, wreg[k4*4+0], acc);
      acc = fmaf(yv.y, wreg[k4*4+1], acc);
      acc = fmaf(yv.z, wreg[k4*4+2], acc);
      acc = fmaf(yv.w, wreg[k4*4+3], acc);
    }
    hcat[(b*NN + n0 + node)*128 + c] = acc;
    float s1 = acc*av1, s2 = acc*av2;
    #pragma unroll
    for (int off = 32; off > 0; off >>= 1) {
      s1 += __shfl_xor(s1, off); s2 += __shfl_xor(s2, off);
    }
    if (lane == 0) {
      int gg = (b << 12) + n0 + node;
      fv[head*16384 + gg] = s1;
      fv[head*16384 + 8192 + gg] = s2;
    }
  }
}

// ---------------- K6: GAT layer1 aggregation (2 heads) + relu ---------------
__global__ __launch_bounds__(256) void k_agg1(const float* __restrict__ hcat,
                                              const float* __restrict__ fv,
                                              const int* __restrict__ nbr,
                                              float* __restrict__ hagg) {
  int g = blockIdx.x*2 + (threadIdx.x >> 7);
  int c = threadIdx.x & 127;
  int b = g >> 12;
  int head = c >> 6;
  int jj[7];
  #pragma unroll
  for (int t = 0; t < 7; ++t) jj[t] = nbr[g*7 + t];
  float f1 = fv[head*16384 + g];
  const float* f2p = fv + head*16384 + 8192 + (b << 12);
  float e[7], mx = -3.0e38f;
  #pragma unroll
  for (int t = 0; t < 7; ++t) {
    float v = f1 + f2p[jj[t]];
    v = (v >= 0.f) ? v : 0.2f*v;
    e[t] = v; mx = fmaxf(mx, v);
  }
  float wgt[7], s = 0.f;
  #pragma unroll
  for (int t = 0; t < 7; ++t) { wgt[t] = expf(e[t] - mx); s += wgt[t]; }
  float acc = 0.f;
  #pragma unroll
  for (int t = 0; t < 7; ++t)
    acc += (wgt[t]/s) * hcat[((b << 12) + jj[t])*128 + c];
  hagg[g*128 + c] = fmaxf(acc, 0.f);
}

// ---------------- K7: ho = hagg @ W_out + fused f-vectors -------------------
__global__ __launch_bounds__(256) void k_ho(const float* __restrict__ hagg,
                                            const float* __restrict__ Wout,
                                            const float* __restrict__ aout,
                                            float* __restrict__ ho,
                                            float* __restrict__ fo) {
  __shared__ __align__(16) float ht[16*128];
  __shared__ float part[16][64];
  int b = blockIdx.x >> 8, n0 = (blockIdx.x & 255)*16;
  int tid = threadIdx.x;
  int c = tid & 63, g = (tid >> 6) & 1, ng = tid >> 7;
  float wreg[64];
  #pragma unroll
  for (int k = 0; k < 64; ++k) wreg[k] = Wout[(g*64 + k)*64 + c];
  {
    const float4* src = (const float4*)(hagg + (b*NN + n0)*128);
    ((float4*)ht)[tid] = src[tid];
    ((float4*)ht)[tid + 256] = src[tid + 256];
  }
  __syncthreads();
  float accs[8];
  for (int nn = 0; nn < 8; ++nn) {
    int node = ng*8 + nn;
    const float* hr = ht + node*128 + g*64;
    float acc = 0.f;
    #pragma unroll
    for (int k4 = 0; k4 < 16; ++k4) {
      float4 hv = *(const float4*)(hr + k4*4);
      acc = fmaf(hv.x, wreg[k4*4+0], acc);
      acc = fmaf(hv.y, wreg[k4*4+1], acc);
      acc = fmaf(hv.z, wreg[k4*4+2], acc);
      acc = fmaf(hv.w, wreg[k4*4+3], acc);
    }
    accs[nn] = acc;
  }
  if (g == 0) {
    #pragma unroll
    for (int nn = 0; nn < 8; ++nn) part[ng*8 + nn][c] = accs[nn];
  }
  __syncthreads();
  if (g == 1) {
    float av1 = aout[c], av2 = aout[64 + c];
    for (int nn = 0; nn < 8; ++nn) {
      int node = ng*8 + nn;
      float acc = accs[nn] + part[node][c];
      ho[(b*NN + n0 + node)*64 + c] = acc;
      float s1 = acc*av1, s2 = acc*av2;
      #pragma unroll
      for (int off = 32; off > 0; off >>= 1) {
        s1 += __shfl_xor(s1, off); s2 += __shfl_xor(s2, off);
      }
      if (c == 0) {
        int gg = (b << 12) + n0 + node;
        fo[gg] = s1;
        fo[8192 + gg] = s2;
      }
    }
  }
}

// ---------------- K9: layer2 agg + elu + log_softmax ------------------------
__global__ __launch_bounds__(256) void k_agg2(const float* __restrict__ ho,
                                              const float* __restrict__ fo,
                                              const int* __restrict__ nbr,
                                              float* __restrict__ zbuf) {
  int g = blockIdx.x*4 + (threadIdx.x >> 6);
  int c = threadIdx.x & 63;
  int b = g >> 12;
  int jj[7];
  #pragma unroll
  for (int t = 0; t < 7; ++t) jj[t] = nbr[g*7 + t];
  float f1 = fo[g];
  const float* f2p = fo + 8192 + (b << 12);
  float e[7], mx = -3.0e38f;
  #pragma unroll
  for (int t = 0; t < 7; ++t) {
    float v = f1 + f2p[jj[t]];
    v = (v >= 0.f) ? v : 0.2f*v;
    e[t] = v; mx = fmaxf(mx, v);
  }
  float wgt[7], s = 0.f;
  #pragma unroll
  for (int t = 0; t < 7; ++t) { wgt[t] = expf(e[t] - mx); s += wgt[t]; }
  float acc = 0.f;
  #pragma unroll
  for (int t = 0; t < 7; ++t)
    acc += (wgt[t]/s) * ho[((b << 12) + jj[t])*64 + c];
  float v = (acc > 0.f) ? acc : expm1f(acc);
  float mm = v;
  #pragma unroll
  for (int off = 32; off > 0; off >>= 1) mm = fmaxf(mm, __shfl_xor(mm, off));
  float ex = expf(v - mm), ss = ex;
  #pragma unroll
  for (int off = 32; off > 0; off >>= 1) ss += __shfl_xor(ss, off);
  zbuf[g*64 + c] = v - mm - logf(ss);
}

// ---------------- K10: ConvTranspose2d v4 (round-9 proven) ------------------
__global__ __launch_bounds__(256, 4) void k_convt4(const float* __restrict__ z,
                                                   const float* __restrict__ wT,
                                                   const float* __restrict__ bias,
                                                   float* __restrict__ out) {
  __shared__ __align__(16) float lds[8704];    // 34816 B
  float* zt = lds;              // [2 rows][64 ci][36]
  float* ws = lds + 4608;       // [64 ci][64 co]
  float* so = lds;              // [64 co][65] epilogue alias

  int oy = blockIdx.x, xh = blockIdx.y, b = blockIdx.z;
  int r = oy >> 1, pi = oy & 1;
  int tid = threadIdx.x;
  int colo = tid & 15, pgrp = tid >> 4;
  int co4 = colo*4, m0 = pgrp*2;
  int ix0 = xh*32;

  int nrows = pi ? 2 : 1;
  for (int row = 0; row < nrows; ++row) {
    int iy = r + row;
    const float* zsrc = z + (((b << 12) + iy*64) << 6);
    float4 v[3];
    #pragma unroll
    for (int j = 0; j < 3; ++j) {
      int chunk = tid + j*256;                 // 528 chunks = 33 ix x 16 ci4
      float4 vv = {0.f, 0.f, 0.f, 0.f};
      if (chunk < 528) {
        int ix = chunk >> 4, ci4 = (chunk & 15) << 2;
        int ixg = ix0 + ix;
        if (ixg < 64 && iy < 64) vv = *(const float4*)(zsrc + ixg*64 + ci4);
      }
      v[j] = vv;
    }
    #pragma unroll
    for (int j = 0; j < 3; ++j) {
      int chunk = tid + j*256;
      if (chunk < 528) {
        int ix = chunk >> 4, ci4 = (chunk & 15) << 2;
        zt[row*2304 + (ci4+0)*36 + ix] = v[j].x;
        zt[row*2304 + (ci4+1)*36 + ix] = v[j].y;
        zt[row*2304 + (ci4+2)*36 + ix] = v[j].z;
        zt[row*2304 + (ci4+3)*36 + ix] = v[j].w;
      }
    }
  }

  float acc[2][2][4];
  {
    float4 bv = *(const float4*)&bias[co4];
    #pragma unroll
    for (int chi = 0; chi < 2; ++chi)
      #pragma unroll
      for (int k = 0; k < 2; ++k) {
        acc[chi][k][0] = bv.x; acc[chi][k][1] = bv.y;
        acc[chi][k][2] = bv.z; acc[chi][k][3] = bv.w;
      }
  }

  int kys[2], rows[2], nky;
  if (pi == 0) { kys[0] = 1; rows[0] = 0; nky = 1; }
  else         { kys[0] = 2; rows[0] = 0; kys[1] = 0; rows[1] = 1; nky = 2; }

  for (int t = 0; t < nky; ++t) {
    const float* zrow = zt + rows[t]*2304;
    for (int kx = 0; kx < 3; ++kx) {
      const float* wsrc = wT + (kys[t]*3 + kx)*4096;
      __syncthreads();
      {
        float4 wv4[4];
        #pragma unroll
        for (int j = 0; j < 4; ++j)
          wv4[j] = *(const float4*)(wsrc + (tid + j*256)*4);
        #pragma unroll
        for (int j = 0; j < 4; ++j)
          *(float4*)&ws[(tid + j*256)*4] = wv4[j];
      }
      __syncthreads();
      const int chi = (kx == 1) ? 0 : 1;
      const int xoff = (kx == 0) ? 1 : 0;
      float* ap = &acc[chi][0][0];
      for (int ci = 0; ci < 64; ++ci) {
        float4 wv = *(const float4*)&ws[ci*64 + co4];
        const float* zp = zrow + ci*36 + m0;
        float z0, z1;
        if (xoff == 0) { float2 za = *(const float2*)zp; z0 = za.x; z1 = za.y; }
        else           { float2 za = *(const float2*)zp; z0 = za.y; z1 = zp[2]; }
        ap[0] = fmaf(z0, wv.x, ap[0]);
        ap[1] = fmaf(z0, wv.y, ap[1]);
        ap[2] = fmaf(z0, wv.z, ap[2]);
        ap[3] = fmaf(z0, wv.w, ap[3]);
        ap[4] = fmaf(z1, wv.x, ap[4]);
        ap[5] = fmaf(z1, wv.y, ap[5]);
        ap[6] = fmaf(z1, wv.z, ap[6]);
        ap[7] = fmaf(z1, wv.w, ap[7]);
      }
    }
  }

  __syncthreads();
  #pragma unroll
  for (int chi = 0; chi < 2; ++chi)
    #pragma unroll
    for (int k = 0; k < 2; ++k)
      #pragma unroll
      for (int cc = 0; cc < 4; ++cc)
        so[(co4 + cc)*65 + 2*(m0 + k) + chi] = acc[chi][k][cc];
  __syncthreads();
  for (int idx = tid; idx < 4096; idx += 256) {
    int co = idx >> 6, ox = idx & 63;
    out[(((b << 6) + co)*128 + oy)*128 + xh*64 + ox] = so[co*65 + ox];
  }
}

// ---------------- launch ----------------------------------------------------
extern "C" void kernel_launch(void* const* d_in, const int* in_sizes, int n_in,
                              void* d_out, int out_size, void* d_ws, size_t ws_size,
                              hipStream_t stream) {
  const float* x      = (const float*)d_in[0];
  const float* w_head = (const float*)d_in[1];
  const float* b_head = (const float*)d_in[2];
  const float* W0     = (const float*)d_in[3];
  const float* a0     = (const float*)d_in[4];
  const float* W1     = (const float*)d_in[5];
  const float* a1     = (const float*)d_in[6];
  const float* W_out  = (const float*)d_in[7];
  const float* a_out  = (const float*)d_in[8];
  const float* w_last = (const float*)d_in[9];
  const float* b_last = (const float*)d_in[10];
  float* out = (float*)d_out;

  float* wsf = (float*)d_ws;
  int*   wsi = (int*)d_ws;
  float* yn   = wsf + OF_YN;
  float* sq   = wsf + OF_SQ;
  float* hcat = wsf + OF_HCAT;
  float* fv   = wsf + OF_FV;
  float* hagg = wsf + OF_HAGG;
  float* ho   = wsf + OF_HO;
  float* fo   = wsf + OF_FO;
  float* zbuf = wsf + OF_Z;
  float* pd   = wsf + OF_PD;
  int*   pidx = wsi + OF_PI;
  int*   nbr  = wsi + OF_NBR;
  float* wT   = wsf + OF_WT;
  float* whT  = wsf + OF_WHT;
  unsigned short* ynh = (unsigned short*)(wsf + OF_YNH);
  unsigned short* ynl = (unsigned short*)(wsf + OF_YNL);

  hipLaunchKernelGGL(k_prep,  dim3(214), dim3(256), 0, stream, w_last, w_head, wT, whT);
  hipLaunchKernelGGL(k_head,  dim3(1024), dim3(256), 0, stream, x, whT, b_head, yn, sq, ynh, ynl);
  hipLaunchKernelGGL(k_knn9,  dim3(64, NCH, 2), dim3(256), 0, stream, ynh, ynl, sq, pd, pidx);
  hipLaunchKernelGGL(k_hm,    dim3(544), dim3(256), 0, stream, yn, W0, W1, a0, a1, hcat, fv, pd, pidx, nbr);
  hipLaunchKernelGGL(k_agg1,  dim3(4096), dim3(256), 0, stream, hcat, fv, nbr, hagg);
  hipLaunchKernelGGL(k_ho,    dim3(512), dim3(256), 0, stream, hagg, W_out, a_out, ho, fo);
  hipLaunchKernelGGL(k_agg2,  dim3(2048), dim3(256), 0, stream, ho, fo, nbr, zbuf);
  hipLaunchKernelGGL(k_convt4, dim3(128, 2, 2), dim3(256), 0, stream, zbuf, wT, b_last, out);
}